// Round 5
// baseline (137.310 us; speedup 1.0000x reference)
//
#include <hip/hip_runtime.h>

// Neural stack, closed form. Round 11: two rows in flight per wave + XCD
// batch affinity.
// R10 showed balance is solved (occ 70%) but time pinned at 45us with VALU
// 35% -> per-row serial chain (scan ~150cy -> extract -> L3 gather ~700cy)
// is the floor. R11: (1) each wave runs a PAIR of rows through one chunk
// loop - two independent scan chains + combined 8-load gather bursts = 2x
// ILP/MLP per wave; (2) block->batch map puts all 16 blocks of a batch on
// one XCD (bid%8 round-robin assumption) so gathers hit the 4MB XCD L2
// instead of L3.
//
// s_j^(t) = relu(d_j - relu(max_{j<tau<=t} G_tau - H_j)),
//   G_tau = U_tau - Dp_{tau-1}, H_j = U_j - Dp_j  (prefix sums of u, d).
// Per row t (p = t - j): M = exclusive prefix-MAX of G, C = exclusive
// prefix-SUM of s, coeff = min(s, relu(1-C)); exactly 0 once C >= 1.

#define TT 512
#define BB 128
#define EE 256
#define NBLOCK 2048                 // 16 g x 128 b; 8 blocks/CU
#define SEEDN 128                   // rows 0..127 statically paired to waves

typedef float v4f __attribute__((ext_vector_type(4)));

// packed per-(b,t): {G, H, d, 0}
__device__ v4f g_GHD[BB * TT];
__device__ unsigned g_ctr[BB * 16];   // per-batch row queue, 64B padded

template <int CTRL, int RM>
__device__ __forceinline__ float dppmov(float o, float s) {
  return __int_as_float(__builtin_amdgcn_update_dpp(
      __float_as_int(o), __float_as_int(s), CTRL, RM, 0xf, false));
}

__device__ __forceinline__ float readlanef(float v, int l) {
  return __int_as_float(__builtin_amdgcn_readlane(__float_as_int(v), l));
}

// wave64 inclusive max-scan (identity -inf)
__device__ __forceinline__ float scan_max64(float v) {
  const float NI = -__builtin_inff();
  v = fmaxf(v, dppmov<0x111, 0xf>(NI, v));   // row_shr:1
  v = fmaxf(v, dppmov<0x112, 0xf>(NI, v));   // row_shr:2
  v = fmaxf(v, dppmov<0x114, 0xf>(NI, v));   // row_shr:4
  v = fmaxf(v, dppmov<0x118, 0xf>(NI, v));   // row_shr:8
  v = fmaxf(v, dppmov<0x142, 0xa>(NI, v));   // row_bcast:15 -> rows 1,3
  v = fmaxf(v, dppmov<0x143, 0xc>(NI, v));   // row_bcast:31 -> rows 2,3
  return v;
}

// wave64 inclusive sum-scan (identity 0)
__device__ __forceinline__ float scan_add64(float v) {
  v += dppmov<0x111, 0xf>(0.f, v);
  v += dppmov<0x112, 0xf>(0.f, v);
  v += dppmov<0x114, 0xf>(0.f, v);
  v += dppmov<0x118, 0xf>(0.f, v);
  v += dppmov<0x142, 0xa>(0.f, v);
  v += dppmov<0x143, 0xc>(0.f, v);
  return v;
}

// whole-wave shift right by 1 (lane0 <- carry)
__device__ __forceinline__ float wshr1(float carry, float v) {
  return __int_as_float(__builtin_amdgcn_update_dpp(
      __float_as_int(carry), __float_as_int(v), 0x138, 0xf, 0xf, false));
}

// ---------------------------------------------------------------------------
// Kernel A: per-batch f64 prefix sums of u,d -> packed (G,H,d) table,
// plus per-batch queue seeding. One wave per b.
// ---------------------------------------------------------------------------
__global__ __launch_bounds__(64) void precompute_kernel(
    const float* __restrict__ u, const float* __restrict__ d) {
  const int b = blockIdx.x;
  const int lane = threadIdx.x;

  if (lane == 0) g_ctr[b * 16] = SEEDN;

  double su[8], sv[8];
  float dv[8];
#pragma unroll
  for (int c = 0; c < 8; ++c) {
    const int t = c * 64 + lane;
    const float uv = u[t * BB + b];
    const float dd = d[t * BB + b];
    dv[c] = dd;
    su[c] = (double)uv;
    sv[c] = (double)dd;
  }
#pragma unroll
  for (int o = 1; o < 64; o <<= 1) {
#pragma unroll
    for (int c = 0; c < 8; ++c) {
      const double yu = __shfl_up(su[c], o);
      const double yv = __shfl_up(sv[c], o);
      if (lane >= o) { su[c] += yu; sv[c] += yv; }
    }
  }
  double oU = 0.0, oD = 0.0;
#pragma unroll
  for (int c = 0; c < 8; ++c) {
    const double U = oU + su[c];
    const double D = oD + sv[c];
    v4f w;
    w.x = (float)(U - (D - (double)dv[c]));  // G_t = U_t - Dp_{t-1}
    w.y = (float)(U - D);                    // H_t = U_t - Dp_t
    w.z = dv[c];
    w.w = 0.f;
    g_GHD[b * TT + c * 64 + lane] = w;
    oU += __shfl(su[c], 63);
    oD += __shfl(sv[c], 63);
  }
}

// ---------------------------------------------------------------------------
// Gather helpers. m must be nonzero on entry; unused slots alias slot 0
// with a zero coefficient (branch-free dummy loads, L1-hot).
// ---------------------------------------------------------------------------
__device__ __forceinline__ void gather4(unsigned long long& m, float coeff,
                                        int tmb, const v4f* __restrict__ vb,
                                        int lane, v4f& acc) {
  const int l0 = __ffsll(m) - 1; m &= m - 1;
  int k1 = l0, k2 = l0, k3 = l0;
  float f1 = 0.f, f2 = 0.f, f3 = 0.f;
  if (m) { k1 = __ffsll(m) - 1; m &= m - 1; f1 = 1.f; }
  if (m) { k2 = __ffsll(m) - 1; m &= m - 1; f2 = 1.f; }
  if (m) { k3 = __ffsll(m) - 1; m &= m - 1; f3 = 1.f; }

  const float c0 = readlanef(coeff, l0);
  const float c1 = f1 * readlanef(coeff, k1);
  const float c2 = f2 * readlanef(coeff, k2);
  const float c3 = f3 * readlanef(coeff, k3);

  const v4f y0 = vb[((tmb - l0) << 13) + lane];
  const v4f y1 = vb[((tmb - k1) << 13) + lane];
  const v4f y2 = vb[((tmb - k2) << 13) + lane];
  const v4f y3 = vb[((tmb - k3) << 13) + lane];

  acc += c0 * y0;
  acc += c1 * y1;
  acc += c2 * y2;
  acc += c3 * y3;
}

__device__ __forceinline__ void gather8(unsigned long long& m, float coeff,
                                        int tmb, const v4f* __restrict__ vb,
                                        int lane, v4f& acc) {
  int kk[8];
  float ff[8];
  const int l0 = __ffsll(m) - 1; m &= m - 1;
  kk[0] = l0; ff[0] = 1.f;
#pragma unroll
  for (int z = 1; z < 8; ++z) {
    if (m) { kk[z] = __ffsll(m) - 1; m &= m - 1; ff[z] = 1.f; }
    else   { kk[z] = l0; ff[z] = 0.f; }
  }
  float cc[8];
#pragma unroll
  for (int z = 0; z < 8; ++z) cc[z] = ff[z] * readlanef(coeff, kk[z]);
  v4f yy[8];
#pragma unroll
  for (int z = 0; z < 8; ++z) yy[z] = vb[((tmb - kk[z]) << 13) + lane];
#pragma unroll
  for (int z = 0; z < 8; ++z) acc += cc[z] * yy[z];
}

// ---------------------------------------------------------------------------
// Two rows' walks, interleaved through one chunk loop. tB < 0 => inactive.
// Independent scan chains double VALU ILP; combined gathers double MLP.
// ---------------------------------------------------------------------------
__device__ void do_row_pair(int tA, int tB, int b, const float* __restrict__ v,
                            float* __restrict__ out, int lane) {
  const v4f* __restrict__ GHD = g_GHD + b * TT;
  const v4f* __restrict__ vb = (const v4f*)(v + b * EE);
  const float NI = -__builtin_inff();

  bool aA = (tA >= 0), aB = (tB >= 0);
  v4f accA = {0.f, 0.f, 0.f, 0.f};
  v4f accB = {0.f, 0.f, 0.f, 0.f};
  float CcA = 0.f, CcB = 0.f;
  float McA = NI, McB = NI;
  int baseA = 0, baseB = 0;

  int j0 = tA - lane;
  v4f ghA = GHD[(aA && j0 >= 0) ? j0 : 0];
  j0 = tB - lane;
  v4f ghB = GHD[(aB && j0 >= 0) ? j0 : 0];

  while (aA | aB) {
    unsigned long long mA = 0ull, mB = 0ull;
    float coeffA = 0.f, coeffB = 0.f;
    float csumA = 0.f, csumB = 0.f;
    float gmaxA = NI, gmaxB = NI;
    v4f ghnA = ghA, ghnB = ghB;

    if (aA) {
      const int jn = tA - (baseA + 64 + lane);
      ghnA = GHD[jn < 0 ? 0 : jn];
      const bool in = (baseA + lane <= tA);
      const float Gv = in ? ghA.x : NI;
      const float Hv = in ? ghA.y : 0.f;
      const float dvv = in ? ghA.z : 0.f;
      gmaxA = scan_max64(Gv);
      const float Mex = fmaxf(wshr1(McA, gmaxA), McA);
      const float s = fmaxf(dvv - fmaxf(Mex - Hv, 0.f), 0.f);
      csumA = scan_add64(s);
      const float Cex = wshr1(0.f, csumA) + CcA;
      coeffA = fminf(s, fmaxf(1.f - Cex, 0.f));
      mA = __ballot(coeffA > 0.f);
    }
    if (aB) {
      const int jn = tB - (baseB + 64 + lane);
      ghnB = GHD[jn < 0 ? 0 : jn];
      const bool in = (baseB + lane <= tB);
      const float Gv = in ? ghB.x : NI;
      const float Hv = in ? ghB.y : 0.f;
      const float dvv = in ? ghB.z : 0.f;
      gmaxB = scan_max64(Gv);
      const float Mex = fmaxf(wshr1(McB, gmaxB), McB);
      const float s = fmaxf(dvv - fmaxf(Mex - Hv, 0.f), 0.f);
      csumB = scan_add64(s);
      const float Cex = wshr1(0.f, csumB) + CcB;
      coeffB = fminf(s, fmaxf(1.f - Cex, 0.f));
      mB = __ballot(coeffB > 0.f);
    }

    // combined phase: 4+4 loads per iteration, compiler interleaves
    while (mA != 0ull && mB != 0ull) {
      gather4(mA, coeffA, tA - baseA, vb, lane, accA);
      gather4(mB, coeffB, tB - baseB, vb, lane, accB);
    }
    // single-side tails: 8-deep
    while (mA != 0ull) gather8(mA, coeffA, tA - baseA, vb, lane, accA);
    while (mB != 0ull) gather8(mB, coeffB, tB - baseB, vb, lane, accB);

    if (aA) {
      CcA += readlanef(csumA, 63);
      McA = fmaxf(McA, readlanef(gmaxA, 63));
      baseA += 64;
      if (CcA >= 1.f || baseA > tA) {
        v4f* op = (v4f*)(out + ((size_t)tA * BB + b) * EE);
        __builtin_nontemporal_store(accA, op + lane);
        accA = (v4f){0.f, 0.f, 0.f, 0.f};
        aA = false;
      } else {
        ghA = ghnA;
      }
    }
    if (aB) {
      CcB += readlanef(csumB, 63);
      McB = fmaxf(McB, readlanef(gmaxB, 63));
      baseB += 64;
      if (CcB >= 1.f || baseB > tB) {
        v4f* op = (v4f*)(out + ((size_t)tB * BB + b) * EE);
        __builtin_nontemporal_store(accB, op + lane);
        accB = (v4f){0.f, 0.f, 0.f, 0.f};
        aB = false;
      } else {
        ghB = ghnB;
      }
    }
  }
}

// ---------------------------------------------------------------------------
// Kernel B: per-batch work stealing, 2 rows per grab, XCD batch affinity.
// bid -> b = ((bid&7)<<4) | ((bid>>3)&15), g = bid>>7: all 16 blocks of a
// batch share bid%8 -> same XCD (round-robin dispatch heuristic), so the
// batch's 512KB v-slice + table stay in that XCD's L2.
// Wave wb = g*4+wave statically takes rows {2wb, 2wb+1} (deepest-first:
// t = 511-n), then steals pairs from g_ctr[b].
// ---------------------------------------------------------------------------
__launch_bounds__(256)
__global__ void stack_kernel(const float* __restrict__ v,
                             float* __restrict__ out) {
  const int bid = blockIdx.x;
  const int b = ((bid & 7) << 4) | ((bid >> 3) & 15);
  const int g = bid >> 7;                 // 0..15
  const int wave = threadIdx.x >> 6;
  const int lane = threadIdx.x & 63;
  const int wb = (g << 2) | wave;         // 0..63

  unsigned n = (unsigned)wb * 2u;         // static first pair

  while (n < TT) {
    const int tA = (TT - 1) - (int)n;
    const int tB = (n + 1 < TT) ? (TT - 1) - (int)(n + 1) : -1;
    do_row_pair(tA, tB, b, v, out, lane);
    unsigned nx = 0;
    if (lane == 0) nx = atomicAdd(&g_ctr[b * 16], 2u);
    n = (unsigned)__builtin_amdgcn_readfirstlane((int)nx);
  }
}

extern "C" void kernel_launch(void* const* d_in, const int* in_sizes, int n_in,
                              void* d_out, int out_size, void* d_ws,
                              size_t ws_size, hipStream_t stream) {
  const float* v = (const float*)d_in[0];
  const float* u = (const float*)d_in[1];
  const float* dd = (const float*)d_in[2];
  float* out = (float*)d_out;
  (void)in_sizes; (void)n_in; (void)out_size; (void)d_ws; (void)ws_size;

  hipLaunchKernelGGL(precompute_kernel, dim3(BB), dim3(64), 0, stream, u, dd);
  hipLaunchKernelGGL(stack_kernel, dim3(NBLOCK), dim3(256), 0, stream,
                     v, out);
}

// Round 6
// 125.853 us; speedup vs baseline: 1.0910x; 1.0910x over previous
//
#include <hip/hip_runtime.h>

// Neural stack, closed form. Round 12: GROUPED WALK — one wave computes 4
// consecutive outputs (tg..tg+3) in a single pass over j, sharing v-row
// gathers across all 4 accumulators.
// R7/R10/R11 all pinned at ~45us dispatch across wildly different
// occupancy/ILP -> bandwidth wall on gather reads (~1.3GB/dispatch at
// ~29TB/s ~ L2/L3 ceiling). Sharing each 4KB v-row load across 4 outputs
// cuts that traffic ~3.5x. Per chunk: 1 shared max-scan, 4 sum-scans
// (collapsing to 1 once the 4 running maxes converge - almost always after
// chunk 0), union ballot, each extracted row FMA'd into 4 accs.
//
// s_j^(t) = relu(d_j - relu(max_{j<tau<=t} G_tau - H_j)),
//   G_tau = U_tau - Dp_{tau-1}, H_j = U_j - Dp_j  (prefix sums of u, d).
// coeff = min(s, relu(1-C)), C = excl suffix sum from top; 0 once C >= 1.
// Entries j in (tg, tg+i] for output i (<=3 of them) are handled by a
// scalar prologue; the shared walk covers j <= tg with per-output carries
// MK_i (max) and Cc_i (sum).

#define TT 512
#define BB 128
#define EE 256
#define NBLOCK 2048                 // 16 g x 128 b; 8 blocks/CU
#define NGRP 128                    // groups of 4 rows per batch
#define SEEDN 64                    // groups 0..63 static to the 64 waves/b

typedef float v4f __attribute__((ext_vector_type(4)));

// packed per-(b,t): {G, H, d, 0}
__device__ v4f g_GHD[BB * TT];
__device__ unsigned g_ctr[BB * 16];   // per-batch group queue, 64B padded

template <int CTRL, int RM>
__device__ __forceinline__ float dppmov(float o, float s) {
  return __int_as_float(__builtin_amdgcn_update_dpp(
      __float_as_int(o), __float_as_int(s), CTRL, RM, 0xf, false));
}

__device__ __forceinline__ float readlanef(float v, int l) {
  return __int_as_float(__builtin_amdgcn_readlane(__float_as_int(v), l));
}

// wave64 inclusive max-scan (identity -inf)
__device__ __forceinline__ float scan_max64(float v) {
  const float NI = -__builtin_inff();
  v = fmaxf(v, dppmov<0x111, 0xf>(NI, v));   // row_shr:1
  v = fmaxf(v, dppmov<0x112, 0xf>(NI, v));   // row_shr:2
  v = fmaxf(v, dppmov<0x114, 0xf>(NI, v));   // row_shr:4
  v = fmaxf(v, dppmov<0x118, 0xf>(NI, v));   // row_shr:8
  v = fmaxf(v, dppmov<0x142, 0xa>(NI, v));   // row_bcast:15 -> rows 1,3
  v = fmaxf(v, dppmov<0x143, 0xc>(NI, v));   // row_bcast:31 -> rows 2,3
  return v;
}

// wave64 inclusive sum-scan (identity 0)
__device__ __forceinline__ float scan_add64(float v) {
  v += dppmov<0x111, 0xf>(0.f, v);
  v += dppmov<0x112, 0xf>(0.f, v);
  v += dppmov<0x114, 0xf>(0.f, v);
  v += dppmov<0x118, 0xf>(0.f, v);
  v += dppmov<0x142, 0xa>(0.f, v);
  v += dppmov<0x143, 0xc>(0.f, v);
  return v;
}

// whole-wave shift right by 1 (lane0 <- carry)
__device__ __forceinline__ float wshr1(float carry, float v) {
  return __int_as_float(__builtin_amdgcn_update_dpp(
      __float_as_int(carry), __float_as_int(v), 0x138, 0xf, 0xf, false));
}

__device__ __forceinline__ float relu(float x) { return fmaxf(x, 0.f); }

// ---------------------------------------------------------------------------
// Kernel A: per-batch f64 prefix sums of u,d -> packed (G,H,d) table,
// plus per-batch queue seeding. One wave per b.
// ---------------------------------------------------------------------------
__global__ __launch_bounds__(64) void precompute_kernel(
    const float* __restrict__ u, const float* __restrict__ d) {
  const int b = blockIdx.x;
  const int lane = threadIdx.x;

  if (lane == 0) g_ctr[b * 16] = SEEDN;

  double su[8], sv[8];
  float dv[8];
#pragma unroll
  for (int c = 0; c < 8; ++c) {
    const int t = c * 64 + lane;
    const float uv = u[t * BB + b];
    const float dd = d[t * BB + b];
    dv[c] = dd;
    su[c] = (double)uv;
    sv[c] = (double)dd;
  }
#pragma unroll
  for (int o = 1; o < 64; o <<= 1) {
#pragma unroll
    for (int c = 0; c < 8; ++c) {
      const double yu = __shfl_up(su[c], o);
      const double yv = __shfl_up(sv[c], o);
      if (lane >= o) { su[c] += yu; sv[c] += yv; }
    }
  }
  double oU = 0.0, oD = 0.0;
#pragma unroll
  for (int c = 0; c < 8; ++c) {
    const double U = oU + su[c];
    const double D = oD + sv[c];
    v4f w;
    w.x = (float)(U - (D - (double)dv[c]));  // G_t = U_t - Dp_{t-1}
    w.y = (float)(U - D);                    // H_t = U_t - Dp_t
    w.z = dv[c];
    w.w = 0.f;
    g_GHD[b * TT + c * 64 + lane] = w;
    oU += __shfl(su[c], 63);
    oD += __shfl(sv[c], 63);
  }
}

// ---------------------------------------------------------------------------
// One group's walk: outputs t = tg, tg+1, tg+2, tg+3 (tg multiple of 4).
// ---------------------------------------------------------------------------
__device__ void do_group(int tg, int b, const float* __restrict__ v,
                         float* __restrict__ out, int lane) {
  const v4f* __restrict__ GHD = g_GHD + b * TT;
  const v4f* __restrict__ vb = (const v4f*)(v + b * EE);
  const float NI = -__builtin_inff();

  v4f acc0 = {0.f, 0.f, 0.f, 0.f};
  v4f acc1 = acc0, acc2 = acc0, acc3 = acc0;
  float Cc0 = 0.f, Cc1, Cc2, Cc3;
  float MK0 = NI, MK1, MK2, MK3;

  // ---- scalar prologue: entries j = tg+1..tg+3 (outputs 1..3 only) ----
  {
    const v4f e1 = GHD[tg + 1];  // uniform loads, broadcast across lanes
    const v4f e2 = GHD[tg + 2];
    const v4f e3 = GHD[tg + 3];
    // s_{tg+k}^{tg+i} = relu(d_k - relu(max(G_{k+1..i}) - H_k))
    const float s11 = e1.z;
    const float s22 = e2.z;
    const float s33 = e3.z;
    const float s12 = relu(e1.z - relu(e2.x - e1.y));
    const float s13 = relu(e1.z - relu(fmaxf(e2.x, e3.x) - e1.y));
    const float s23 = relu(e2.z - relu(e3.x - e2.y));
    // top-down coeffs per output
    const float c11 = fminf(s11, 1.f);
    Cc1 = s11;
    const float c22 = fminf(s22, 1.f);
    float r2 = s22;
    const float c12 = fminf(s12, relu(1.f - r2));
    Cc2 = r2 + s12;
    const float c33 = fminf(s33, 1.f);
    float r3 = s33;
    const float c23 = fminf(s23, relu(1.f - r3));
    r3 += s23;
    const float c13 = fminf(s13, relu(1.f - r3));
    Cc3 = r3 + s13;
    MK1 = e1.x;
    MK2 = fmaxf(e1.x, e2.x);
    MK3 = fmaxf(MK2, e3.x);
    // shared gathers of the 3 top rows
    const v4f y1 = vb[((tg + 1) << 13) + lane];
    const v4f y2 = vb[((tg + 2) << 13) + lane];
    const v4f y3 = vb[((tg + 3) << 13) + lane];
    acc1 += c11 * y1;
    acc2 += c22 * y2;
    acc2 += c12 * y1;
    acc3 += c33 * y3;
    acc3 += c23 * y2;
    acc3 += c13 * y1;
  }

  // ---- shared walk over j <= tg ----
  int j0 = tg - lane;
  v4f gh = GHD[j0 < 0 ? 0 : j0];

  for (int base = 0; base <= tg; base += 64) {
    const int jn = tg - (base + 64 + lane);
    const v4f ghn = GHD[jn < 0 ? 0 : jn];    // next-chunk prefetch

    const bool in = (base + lane <= tg);
    const float Gv = in ? gh.x : NI;
    const float Hv = in ? gh.y : 0.f;
    const float dv = in ? gh.z : 0.f;

    const float gmax = scan_max64(Gv);       // inclusive max, this chunk
    const float mex = wshr1(NI, gmax);       // exclusive within chunk
    const float chmax = readlanef(gmax, 63);

    float c0, c1, c2, c3;
    float dC0, dC1, dC2, dC3;

    if (MK0 == MK3) {
      // carries converged (MK monotone in i) -> one s vector, one scan
      const float s = relu(dv - relu(fmaxf(mex, MK0) - Hv));
      const float cs = scan_add64(s);
      const float ce = wshr1(0.f, cs);
      c0 = fminf(s, relu(1.f - (ce + Cc0)));
      c1 = fminf(s, relu(1.f - (ce + Cc1)));
      c2 = fminf(s, relu(1.f - (ce + Cc2)));
      c3 = fminf(s, relu(1.f - (ce + Cc3)));
      dC0 = dC1 = dC2 = dC3 = readlanef(cs, 63);
    } else {
      // 4 independent chains (chunk 0, typically)
      const float s0 = relu(dv - relu(fmaxf(mex, MK0) - Hv));
      const float s1 = relu(dv - relu(fmaxf(mex, MK1) - Hv));
      const float s2 = relu(dv - relu(fmaxf(mex, MK2) - Hv));
      const float s3 = relu(dv - relu(fmaxf(mex, MK3) - Hv));
      const float cs0 = scan_add64(s0);
      const float cs1 = scan_add64(s1);
      const float cs2 = scan_add64(s2);
      const float cs3 = scan_add64(s3);
      c0 = fminf(s0, relu(1.f - (wshr1(0.f, cs0) + Cc0)));
      c1 = fminf(s1, relu(1.f - (wshr1(0.f, cs1) + Cc1)));
      c2 = fminf(s2, relu(1.f - (wshr1(0.f, cs2) + Cc2)));
      c3 = fminf(s3, relu(1.f - (wshr1(0.f, cs3) + Cc3)));
      dC0 = readlanef(cs0, 63);
      dC1 = readlanef(cs1, 63);
      dC2 = readlanef(cs2, 63);
      dC3 = readlanef(cs3, 63);
    }

    // union gather: each unique j loaded once, FMA'd into all 4 accs
    unsigned long long m = __ballot((c0 + c1 + c2 + c3) > 0.f);
    while (m) {
      const int l0 = __ffsll(m) - 1; m &= m - 1;
      int l1 = l0, l2 = l0, l3 = l0;
      float f1 = 0.f, f2 = 0.f, f3 = 0.f;
      if (m) { l1 = __ffsll(m) - 1; m &= m - 1; f1 = 1.f; }
      if (m) { l2 = __ffsll(m) - 1; m &= m - 1; f2 = 1.f; }
      if (m) { l3 = __ffsll(m) - 1; m &= m - 1; f3 = 1.f; }

      const float a00 = readlanef(c0, l0);
      const float a01 = readlanef(c1, l0);
      const float a02 = readlanef(c2, l0);
      const float a03 = readlanef(c3, l0);
      const float a10 = f1 * readlanef(c0, l1);
      const float a11 = f1 * readlanef(c1, l1);
      const float a12 = f1 * readlanef(c2, l1);
      const float a13 = f1 * readlanef(c3, l1);
      const float a20 = f2 * readlanef(c0, l2);
      const float a21 = f2 * readlanef(c1, l2);
      const float a22 = f2 * readlanef(c2, l2);
      const float a23 = f2 * readlanef(c3, l2);
      const float a30 = f3 * readlanef(c0, l3);
      const float a31 = f3 * readlanef(c1, l3);
      const float a32 = f3 * readlanef(c2, l3);
      const float a33 = f3 * readlanef(c3, l3);

      const v4f y0 = vb[((tg - base - l0) << 13) + lane];
      const v4f y1 = vb[((tg - base - l1) << 13) + lane];
      const v4f y2 = vb[((tg - base - l2) << 13) + lane];
      const v4f y3 = vb[((tg - base - l3) << 13) + lane];

      acc0 += a00 * y0; acc1 += a01 * y0; acc2 += a02 * y0; acc3 += a03 * y0;
      acc0 += a10 * y1; acc1 += a11 * y1; acc2 += a12 * y1; acc3 += a13 * y1;
      acc0 += a20 * y2; acc1 += a21 * y2; acc2 += a22 * y2; acc3 += a23 * y2;
      acc0 += a30 * y3; acc1 += a31 * y3; acc2 += a32 * y3; acc3 += a33 * y3;
    }

    Cc0 += dC0; Cc1 += dC1; Cc2 += dC2; Cc3 += dC3;
    MK0 = fmaxf(MK0, chmax);
    MK1 = fmaxf(MK1, chmax);
    MK2 = fmaxf(MK2, chmax);
    MK3 = fmaxf(MK3, chmax);
    if (Cc0 >= 1.f && Cc1 >= 1.f && Cc2 >= 1.f && Cc3 >= 1.f) break;
    gh = ghn;
  }

  v4f* op0 = (v4f*)(out + ((size_t)(tg + 0) * BB + b) * EE);
  v4f* op1 = (v4f*)(out + ((size_t)(tg + 1) * BB + b) * EE);
  v4f* op2 = (v4f*)(out + ((size_t)(tg + 2) * BB + b) * EE);
  v4f* op3 = (v4f*)(out + ((size_t)(tg + 3) * BB + b) * EE);
  __builtin_nontemporal_store(acc0, op0 + lane);
  __builtin_nontemporal_store(acc1, op1 + lane);
  __builtin_nontemporal_store(acc2, op2 + lane);
  __builtin_nontemporal_store(acc3, op3 + lane);
}

// ---------------------------------------------------------------------------
// Kernel B: per-batch work stealing over GROUPS (4 rows each).
// Block (g,b): b = bid & 127. Wave wb = g*4+wave (0..63) statically takes
// group n = wb (deepest-first: tg = 508 - 4n), then steals single groups
// from g_ctr[b]. All 4 waves of a block share batch b -> locality.
// ---------------------------------------------------------------------------
__launch_bounds__(256)
__global__ void stack_kernel(const float* __restrict__ v,
                             float* __restrict__ out) {
  const int b = blockIdx.x & (BB - 1);
  const int g = blockIdx.x >> 7;          // 0..15
  const int wave = threadIdx.x >> 6;
  const int lane = threadIdx.x & 63;
  const int wb = (g << 2) | wave;         // 0..63

  unsigned n = (unsigned)wb;              // static first group

  while (n < NGRP) {
    const int tg = (TT - 4) - 4 * (int)n;
    do_group(tg, b, v, out, lane);
    unsigned nx = 0;
    if (lane == 0) nx = atomicAdd(&g_ctr[b * 16], 1u);
    n = (unsigned)__builtin_amdgcn_readfirstlane((int)nx);
  }
}

extern "C" void kernel_launch(void* const* d_in, const int* in_sizes, int n_in,
                              void* d_out, int out_size, void* d_ws,
                              size_t ws_size, hipStream_t stream) {
  const float* v = (const float*)d_in[0];
  const float* u = (const float*)d_in[1];
  const float* dd = (const float*)d_in[2];
  float* out = (float*)d_out;
  (void)in_sizes; (void)n_in; (void)out_size; (void)d_ws; (void)ws_size;

  hipLaunchKernelGGL(precompute_kernel, dim3(BB), dim3(64), 0, stream, u, dd);
  hipLaunchKernelGGL(stack_kernel, dim3(NBLOCK), dim3(256), 0, stream,
                     v, out);
}